// Round 10
// baseline (1771.881 us; speedup 1.0000x reference)
//
#include <hip/hip_runtime.h>
#include <hip/hip_bf16.h>
#include <stdint.h>

// Problem constants
#define TT 4
#define BE 16
#define BB 64          // TT * BE
#define CC 512
#define NN 512
#define NH 8
#define GD 64          // CC / NH
#define NW 16          // NN/32 packed words per (b,c) row
#define TAU 0.5f
#define THRESH 1.0f
#define SCALE 0.125f
#define EPS 1e-5f

// ---------------------------------------------------------------------------
// Kernel 1: 1x1-conv + BN + LIF over T -> bit-packed spikes.
// z = w*BE + be. Tile 32c x 256n, 4 waves; wave owns 8 rows (WAVE-UNIFORM ->
// W reads become s_load via readfirstlane, off the LDS pipe), lane owns 4 cols.
// LDS carries only X: 1 ds_read_b128 per 32 FMAs. X double-buffered.
// ---------------------------------------------------------------------------
__global__ __launch_bounds__(256) void conv_bn_lif_kernel(
    const float* __restrict__ x,      // [BB, CC, NN]
    const float* __restrict__ Wq,     // [CC, CC] (out, in)
    const float* __restrict__ Wk,
    const float* __restrict__ Wv,
    const float* __restrict__ bn_g,   // [4, CC]
    const float* __restrict__ bn_b,
    const float* __restrict__ bn_m,
    const float* __restrict__ bn_v,
    uint32_t* __restrict__ qp,        // [BB*CC, NW] packed
    uint32_t* __restrict__ kp,
    uint32_t* __restrict__ vp)
{
    __shared__ float Xs[2][16][256];  // X tile only; rows 1KB (bank-aligned, r/w distinct)

    const int tid = threadIdx.x;
    const int lane = tid & 63;
    const int wave = tid >> 6;
    const int n0 = blockIdx.x * 256;
    const int c0 = blockIdx.y * 32;
    const int z  = blockIdx.z;
    const int be = z & (BE - 1);
    const int w  = z >> 4;

    const float* W = (w == 0) ? Wq : (w == 1) ? Wk : Wv;
    uint32_t* outp = (w == 0) ? qp : (w == 1) ? kp : vp;

    // wave-uniform row base -> scalar (s_load) W accesses
    const int rb = __builtin_amdgcn_readfirstlane(c0 + 8 * wave);
    const float* __restrict__ Wr = W + (size_t)rb * CC;

    float inv_c[8], add_c[8];
#pragma unroll
    for (int i = 0; i < 8; ++i) {
        int c = rb + i;
        float g = bn_g[w * CC + c];
        float b = bn_b[w * CC + c];
        float m = bn_m[w * CC + c];
        float v = bn_v[w * CC + c];
        float inv = g / sqrtf(v + EPS);
        inv_c[i] = inv;
        add_c[i] = b - m * inv;
    }

    float mem[8][4];
#pragma unroll
    for (int i = 0; i < 8; ++i)
#pragma unroll
        for (int j = 0; j < 4; ++j) mem[i][j] = 0.0f;

    // staging map: s=0..3 -> kk = wave + 4s, colf = lane (16B-coalesced)
    for (int t = 0; t < TT; ++t) {
        const int b = t * BE + be;
        const float* xb = x + (size_t)b * CC * NN + n0 + 4 * lane;

        float acc[8][4];
#pragma unroll
        for (int i = 0; i < 8; ++i)
#pragma unroll
            for (int j = 0; j < 4; ++j) acc[i][j] = 0.0f;

        float4 px[4];
        // prologue: k0=0 -> buf0
#pragma unroll
        for (int s = 0; s < 4; ++s)
            px[s] = *(const float4*)&xb[(size_t)(wave + 4 * s) * NN];
#pragma unroll
        for (int s = 0; s < 4; ++s)
            *(float4*)&Xs[0][wave + 4 * s][4 * lane] = px[s];
        __syncthreads();
        // prefetch k0=16
#pragma unroll
        for (int s = 0; s < 4; ++s)
            px[s] = *(const float4*)&xb[(size_t)(16 + wave + 4 * s) * NN];

        int cur = 0;
        for (int k0 = 0; k0 < CC; k0 += 16) {
#pragma unroll
            for (int kk = 0; kk < 16; ++kk) {
                float4 xv = *(float4*)&Xs[cur][kk][4 * lane];
#pragma unroll
                for (int r = 0; r < 8; ++r) {
                    float a = Wr[(size_t)r * CC + k0 + kk];   // uniform -> s_load
                    acc[r][0] += a * xv.x;
                    acc[r][1] += a * xv.y;
                    acc[r][2] += a * xv.z;
                    acc[r][3] += a * xv.w;
                }
            }
            if (k0 + 16 < CC) {
                int nxt = cur ^ 1;
#pragma unroll
                for (int s = 0; s < 4; ++s)
                    *(float4*)&Xs[nxt][wave + 4 * s][4 * lane] = px[s];
                __syncthreads();
                cur = nxt;
                if (k0 + 32 < CC) {
#pragma unroll
                    for (int s = 0; s < 4; ++s)
                        px[s] = *(const float4*)&xb[(size_t)(k0 + 32 + wave + 4 * s) * NN];
                }
            }
        }

        // epilogue: BN + LIF -> nibble -> octet shfl-OR -> packed word
#pragma unroll
        for (int r = 0; r < 8; ++r) {
            uint32_t nib = 0;
#pragma unroll
            for (int j = 0; j < 4; ++j) {
                float y = acc[r][j] * inv_c[r] + add_c[r];
                float m2 = mem[r][j] * TAU + y;
                bool s = m2 > THRESH;
                nib |= (s ? 1u : 0u) << j;
                mem[r][j] = s ? 0.0f : m2;
            }
            uint32_t word = nib << (4 * (lane & 7));
            word |= (uint32_t)__shfl_xor((int)word, 1);
            word |= (uint32_t)__shfl_xor((int)word, 2);
            word |= (uint32_t)__shfl_xor((int)word, 4);
            if ((lane & 7) == 0) {
                outp[(size_t)(b * CC + rb + r) * NW + (n0 >> 5) + (lane >> 3)] = word;
            }
        }
        // t+1 prologue writes buf0; its last reads ended before the final
        // barrier of this t's K-loop -> safe.
    }
}

// ---------------------------------------------------------------------------
// Kernel 2: fused attention + LIF3 on packed spikes (unchanged, verified).
// ---------------------------------------------------------------------------
__global__ __launch_bounds__(256) void attn_lif_kernel(
    const uint32_t* __restrict__ qp,
    const uint32_t* __restrict__ kp,
    const uint32_t* __restrict__ vp,
    uint32_t* __restrict__ s3p)
{
    __shared__ uint32_t kL[64][NW + 1];
    __shared__ uint32_t vL[64][NW + 1];
    __shared__ float    Msh[64][64 + 1];
    __shared__ uint32_t qL[64][5];

    const int tid = threadIdx.x;
    const int nchunk = blockIdx.x;
    const int h = blockIdx.y;
    const int be = blockIdx.z;
    const int d_own = tid >> 2;
    const int nw_own = tid & 3;

    float mem[32];
#pragma unroll
    for (int i = 0; i < 32; ++i) mem[i] = 0.0f;

    for (int t = 0; t < TT; ++t) {
        const int b = t * BE + be;
        const size_t base_row = (size_t)(b * CC + h * GD);

        for (int i = tid; i < 64 * NW; i += 256) {
            int r = i >> 4;
            int w = i & (NW - 1);
            kL[r][w] = kp[(base_row + r) * NW + w];
            vL[r][w] = vp[(base_row + r) * NW + w];
        }
        {
            int r = tid >> 2;
            int w = tid & 3;
            qL[r][w] = qp[(base_row + r) * NW + nchunk * 4 + w];
        }
        __syncthreads();

        for (int e = tid; e < 64 * 64; e += 256) {
            int d = e >> 6;
            int dp = e & 63;
            int s = 0;
#pragma unroll
            for (int w = 0; w < NW; ++w) s += __popc(vL[d][w] & kL[dp][w]);
            Msh[d][dp] = (float)s;
        }
        __syncthreads();

        float acc[32];
#pragma unroll
        for (int i = 0; i < 32; ++i) acc[i] = 0.0f;

        for (int dp = 0; dp < 64; ++dp) {
            float Mv = Msh[d_own][dp];
            uint32_t w = qL[dp][nw_own];
#pragma unroll
            for (int b2 = 0; b2 < 32; ++b2) {
                acc[b2] += ((w >> b2) & 1u) ? Mv : 0.0f;
            }
        }

        uint32_t sw = 0;
#pragma unroll
        for (int b2 = 0; b2 < 32; ++b2) {
            float m2 = mem[b2] * TAU + SCALE * acc[b2];
            bool s = m2 > THRESH;
            sw |= (s ? 1u : 0u) << b2;
            mem[b2] = s ? 0.0f : m2;
        }
        s3p[(base_row + d_own) * NW + nchunk * 4 + nw_own] = sw;
        __syncthreads();
    }
}

// ---------------------------------------------------------------------------
// Kernel 3: projection conv + BN -> fp32 out. Same scalar-A structure.
// Grid (NN/256, CC/32, BB).
// ---------------------------------------------------------------------------
__global__ __launch_bounds__(256) void proj_kernel(
    const uint32_t* __restrict__ s3p,          // [BB*CC, NW] packed
    const float* __restrict__ W,               // [CC, CC]
    const float* __restrict__ bn_g,
    const float* __restrict__ bn_b,
    const float* __restrict__ bn_m,
    const float* __restrict__ bn_v,
    float* __restrict__ out)                   // [BB, CC, NN]
{
    __shared__ float Xs[2][16][256];

    const int tid = threadIdx.x;
    const int lane = tid & 63;
    const int wave = tid >> 6;
    const int n0 = blockIdx.x * 256;
    const int c0 = blockIdx.y * 32;
    const int b = blockIdx.z;

    const int rb = __builtin_amdgcn_readfirstlane(c0 + 8 * wave);
    const float* __restrict__ Wr = W + (size_t)rb * CC;

    float inv_c[8], add_c[8];
#pragma unroll
    for (int i = 0; i < 8; ++i) {
        int c = rb + i;
        float g = bn_g[3 * CC + c];
        float bt = bn_b[3 * CC + c];
        float m = bn_m[3 * CC + c];
        float v = bn_v[3 * CC + c];
        float inv = g / sqrtf(v + EPS);
        inv_c[i] = inv;
        add_c[i] = bt - m * inv;
    }

    float acc[8][4];
#pragma unroll
    for (int i = 0; i < 8; ++i)
#pragma unroll
        for (int j = 0; j < 4; ++j) acc[i][j] = 0.0f;

    // staging: s=0..3 -> kk = wave+4s, cols 4*lane..+3 from packed word
    const int sh = 4 * (lane & 7);
    auto ldw = [&](int k0, int s) -> uint32_t {
        return s3p[(size_t)(b * CC + k0 + wave + 4 * s) * NW + (n0 >> 5) + (lane >> 3)];
    };
    auto expand = [&](uint32_t word) -> float4 {
        float4 xv;
        xv.x = (float)((word >> (sh + 0)) & 1u);
        xv.y = (float)((word >> (sh + 1)) & 1u);
        xv.z = (float)((word >> (sh + 2)) & 1u);
        xv.w = (float)((word >> (sh + 3)) & 1u);
        return xv;
    };

    uint32_t pw[4];
#pragma unroll
    for (int s = 0; s < 4; ++s) pw[s] = ldw(0, s);
#pragma unroll
    for (int s = 0; s < 4; ++s)
        *(float4*)&Xs[0][wave + 4 * s][4 * lane] = expand(pw[s]);
    __syncthreads();
#pragma unroll
    for (int s = 0; s < 4; ++s) pw[s] = ldw(16, s);

    int cur = 0;
    for (int k0 = 0; k0 < CC; k0 += 16) {
#pragma unroll
        for (int kk = 0; kk < 16; ++kk) {
            float4 xv = *(float4*)&Xs[cur][kk][4 * lane];
#pragma unroll
            for (int r = 0; r < 8; ++r) {
                float a = Wr[(size_t)r * CC + k0 + kk];   // uniform -> s_load
                acc[r][0] += a * xv.x;
                acc[r][1] += a * xv.y;
                acc[r][2] += a * xv.z;
                acc[r][3] += a * xv.w;
            }
        }
        if (k0 + 16 < CC) {
            int nxt = cur ^ 1;
#pragma unroll
            for (int s = 0; s < 4; ++s)
                *(float4*)&Xs[nxt][wave + 4 * s][4 * lane] = expand(pw[s]);
            __syncthreads();
            cur = nxt;
            if (k0 + 32 < CC) {
#pragma unroll
                for (int s = 0; s < 4; ++s) pw[s] = ldw(k0 + 32, s);
            }
        }
    }

    float* ob = out + (size_t)b * CC * NN;
#pragma unroll
    for (int r = 0; r < 8; ++r) {
        float4 o;
        o.x = acc[r][0] * inv_c[r] + add_c[r];
        o.y = acc[r][1] * inv_c[r] + add_c[r];
        o.z = acc[r][2] * inv_c[r] + add_c[r];
        o.w = acc[r][3] * inv_c[r] + add_c[r];
        *(float4*)&ob[(size_t)(rb + r) * NN + n0 + 4 * lane] = o;
    }
}

// ---------------------------------------------------------------------------
extern "C" void kernel_launch(void* const* d_in, const int* in_sizes, int n_in,
                              void* d_out, int out_size, void* d_ws, size_t ws_size,
                              hipStream_t stream) {
    const float* x     = (const float*)d_in[0];
    const float* wq    = (const float*)d_in[1];
    const float* wk    = (const float*)d_in[2];
    const float* wv    = (const float*)d_in[3];
    const float* wproj = (const float*)d_in[4];
    const float* bng   = (const float*)d_in[5];
    const float* bnb   = (const float*)d_in[6];
    const float* bnm   = (const float*)d_in[7];
    const float* bnv   = (const float*)d_in[8];

    const size_t PK = (size_t)BB * CC * NW;            // 2 MiB each
    uint32_t* qp  = (uint32_t*)d_ws;
    uint32_t* kp  = qp + PK;
    uint32_t* vp  = kp + PK;
    uint32_t* s3p = vp + PK;                           // total 8 MiB

    dim3 gconv(NN / 256, CC / 32, 3 * BE);             // z = w*16 + be
    conv_bn_lif_kernel<<<gconv, 256, 0, stream>>>(x, wq, wk, wv, bng, bnb, bnm, bnv,
                                                  qp, kp, vp);

    dim3 gattn(4, NH, BE);
    attn_lif_kernel<<<gattn, 256, 0, stream>>>(qp, kp, vp, s3p);

    dim3 gproj(NN / 256, CC / 32, BB);
    proj_kernel<<<gproj, 256, 0, stream>>>(s3p, wproj, bng, bnb, bnm, bnv, (float*)d_out);
}

// Round 11
// 1312.198 us; speedup vs baseline: 1.3503x; 1.3503x over previous
//
#include <hip/hip_runtime.h>
#include <hip/hip_bf16.h>
#include <stdint.h>

// Problem constants
#define TT 4
#define BE 16
#define BB 64          // TT * BE
#define CC 512
#define NN 512
#define NH 8
#define GD 64          // CC / NH
#define NW 16          // NN/32 packed words per (b,c) row
#define TAU 0.5f
#define THRESH 1.0f
#define SCALE 0.125f
#define EPS 1e-5f

// ---------------------------------------------------------------------------
// Kernel 1: 1x1-conv + BN + LIF over T -> bit-packed spikes.
// z = w*BE + be. Tile 32c x 256n, 4 waves; wave owns 8 rows -> W via scalar
// loads (wave-uniform addresses), LDS carries only X (1 b128 per 64 VALU-cyc
// -> VALU-bound). Register windows bounded: xf chunks of 8 kk inside a
// no-unroll h-loop (prevents R10's 128-wide s_load hoist -> scratch spill).
// ---------------------------------------------------------------------------
__global__ __launch_bounds__(256) void conv_bn_lif_kernel(
    const float* __restrict__ x,      // [BB, CC, NN]
    const float* __restrict__ Wq,     // [CC, CC] (out, in)
    const float* __restrict__ Wk,
    const float* __restrict__ Wv,
    const float* __restrict__ bn_g,   // [4, CC]
    const float* __restrict__ bn_b,
    const float* __restrict__ bn_m,
    const float* __restrict__ bn_v,
    uint32_t* __restrict__ qp,        // [BB*CC, NW] packed
    uint32_t* __restrict__ kp,
    uint32_t* __restrict__ vp)
{
    __shared__ float Xs[16][256];     // 16 KB, X tile only

    const int tid = threadIdx.x;
    const int lane = tid & 63;
    const int wave = tid >> 6;
    const int n0 = blockIdx.x * 256;
    const int c0 = blockIdx.y * 32;
    const int z  = blockIdx.z;
    const int be = z & (BE - 1);
    const int w  = z >> 4;

    const float* W = (w == 0) ? Wq : (w == 1) ? Wk : Wv;
    uint32_t* outp = (w == 0) ? qp : (w == 1) ? kp : vp;

    const int rb = __builtin_amdgcn_readfirstlane(c0 + 8 * wave);
    const float* __restrict__ Wr = W + (size_t)rb * CC;

    float inv_c[8], add_c[8];
#pragma unroll
    for (int i = 0; i < 8; ++i) {
        int c = rb + i;
        float g = bn_g[w * CC + c];
        float b = bn_b[w * CC + c];
        float m = bn_m[w * CC + c];
        float v = bn_v[w * CC + c];
        float inv = g / sqrtf(v + EPS);
        inv_c[i] = inv;
        add_c[i] = b - m * inv;
    }

    float mem[8][4];
#pragma unroll
    for (int i = 0; i < 8; ++i)
#pragma unroll
        for (int j = 0; j < 4; ++j) mem[i][j] = 0.0f;

    // staging map: s=0..3 -> f = tid+256s, kk = f>>6, colf = f&63
    const int skk[4] = {tid >> 6, (tid + 256) >> 6, (tid + 512) >> 6, (tid + 768) >> 6};
    const int scf = tid & 63;   // colf identical for all s (tid mod 64)

    for (int t = 0; t < TT; ++t) {
        const int b = t * BE + be;
        const float* xb = x + (size_t)b * CC * NN + n0 + 4 * scf;

        float acc[8][4];
#pragma unroll
        for (int i = 0; i < 8; ++i)
#pragma unroll
            for (int j = 0; j < 4; ++j) acc[i][j] = 0.0f;

        float4 px[4];
        __syncthreads();   // prev-t last-tile reads complete before overwrite
#pragma unroll
        for (int s = 0; s < 4; ++s)
            px[s] = *(const float4*)&xb[(size_t)skk[s] * NN];
#pragma unroll
        for (int s = 0; s < 4; ++s)
            *(float4*)&Xs[skk[s]][4 * scf] = px[s];
        __syncthreads();

        for (int k0 = 0; k0 < CC; k0 += 16) {
            const bool hasNext = (k0 + 16 < CC);
            if (hasNext) {
#pragma unroll
                for (int s = 0; s < 4; ++s)
                    px[s] = *(const float4*)&xb[(size_t)(k0 + 16 + skk[s]) * NN];
            }
#pragma unroll 1
            for (int h = 0; h < 2; ++h) {
                float4 xf[8];
#pragma unroll
                for (int u = 0; u < 8; ++u)
                    xf[u] = *(float4*)&Xs[8 * h + u][4 * lane];
#pragma unroll
                for (int r = 0; r < 8; ++r) {
#pragma unroll
                    for (int u = 0; u < 8; ++u) {
                        float a = Wr[(size_t)r * CC + k0 + 8 * h + u];  // s_load
                        acc[r][0] += a * xf[u].x;
                        acc[r][1] += a * xf[u].y;
                        acc[r][2] += a * xf[u].z;
                        acc[r][3] += a * xf[u].w;
                    }
                }
            }
            if (hasNext) {
                __syncthreads();   // all reads of cur tile done (px long complete)
#pragma unroll
                for (int s = 0; s < 4; ++s)
                    *(float4*)&Xs[skk[s]][4 * scf] = px[s];
                __syncthreads();
            }
        }

        // epilogue: BN + LIF -> nibble -> octet shfl-OR -> packed word
#pragma unroll
        for (int r = 0; r < 8; ++r) {
            uint32_t nib = 0;
#pragma unroll
            for (int j = 0; j < 4; ++j) {
                float y = acc[r][j] * inv_c[r] + add_c[r];
                float m2 = mem[r][j] * TAU + y;
                bool s = m2 > THRESH;
                nib |= (s ? 1u : 0u) << j;
                mem[r][j] = s ? 0.0f : m2;
            }
            uint32_t word = nib << (4 * (lane & 7));
            word |= (uint32_t)__shfl_xor((int)word, 1);
            word |= (uint32_t)__shfl_xor((int)word, 2);
            word |= (uint32_t)__shfl_xor((int)word, 4);
            if ((lane & 7) == 0) {
                outp[(size_t)(b * CC + rb + r) * NW + (n0 >> 5) + (lane >> 3)] = word;
            }
        }
    }
}

// ---------------------------------------------------------------------------
// Kernel 2: fused attention + LIF3 on packed spikes (unchanged, verified).
// ---------------------------------------------------------------------------
__global__ __launch_bounds__(256) void attn_lif_kernel(
    const uint32_t* __restrict__ qp,
    const uint32_t* __restrict__ kp,
    const uint32_t* __restrict__ vp,
    uint32_t* __restrict__ s3p)
{
    __shared__ uint32_t kL[64][NW + 1];
    __shared__ uint32_t vL[64][NW + 1];
    __shared__ float    Msh[64][64 + 1];
    __shared__ uint32_t qL[64][5];

    const int tid = threadIdx.x;
    const int nchunk = blockIdx.x;
    const int h = blockIdx.y;
    const int be = blockIdx.z;
    const int d_own = tid >> 2;
    const int nw_own = tid & 3;

    float mem[32];
#pragma unroll
    for (int i = 0; i < 32; ++i) mem[i] = 0.0f;

    for (int t = 0; t < TT; ++t) {
        const int b = t * BE + be;
        const size_t base_row = (size_t)(b * CC + h * GD);

        for (int i = tid; i < 64 * NW; i += 256) {
            int r = i >> 4;
            int w = i & (NW - 1);
            kL[r][w] = kp[(base_row + r) * NW + w];
            vL[r][w] = vp[(base_row + r) * NW + w];
        }
        {
            int r = tid >> 2;
            int w = tid & 3;
            qL[r][w] = qp[(base_row + r) * NW + nchunk * 4 + w];
        }
        __syncthreads();

        for (int e = tid; e < 64 * 64; e += 256) {
            int d = e >> 6;
            int dp = e & 63;
            int s = 0;
#pragma unroll
            for (int w = 0; w < NW; ++w) s += __popc(vL[d][w] & kL[dp][w]);
            Msh[d][dp] = (float)s;
        }
        __syncthreads();

        float acc[32];
#pragma unroll
        for (int i = 0; i < 32; ++i) acc[i] = 0.0f;

        for (int dp = 0; dp < 64; ++dp) {
            float Mv = Msh[d_own][dp];
            uint32_t w = qL[dp][nw_own];
#pragma unroll
            for (int b2 = 0; b2 < 32; ++b2) {
                acc[b2] += ((w >> b2) & 1u) ? Mv : 0.0f;
            }
        }

        uint32_t sw = 0;
#pragma unroll
        for (int b2 = 0; b2 < 32; ++b2) {
            float m2 = mem[b2] * TAU + SCALE * acc[b2];
            bool s = m2 > THRESH;
            sw |= (s ? 1u : 0u) << b2;
            mem[b2] = s ? 0.0f : m2;
        }
        s3p[(base_row + d_own) * NW + nchunk * 4 + nw_own] = sw;
        __syncthreads();
    }
}

// ---------------------------------------------------------------------------
// Kernel 3: projection conv + BN -> fp32 out. Same scalar-W structure, no LIF.
// Grid (NN/256, CC/32, BB).
// ---------------------------------------------------------------------------
__global__ __launch_bounds__(256) void proj_kernel(
    const uint32_t* __restrict__ s3p,          // [BB*CC, NW] packed
    const float* __restrict__ W,               // [CC, CC]
    const float* __restrict__ bn_g,
    const float* __restrict__ bn_b,
    const float* __restrict__ bn_m,
    const float* __restrict__ bn_v,
    float* __restrict__ out)                   // [BB, CC, NN]
{
    __shared__ float Xs[16][256];

    const int tid = threadIdx.x;
    const int lane = tid & 63;
    const int wave = tid >> 6;
    const int n0 = blockIdx.x * 256;
    const int c0 = blockIdx.y * 32;
    const int b = blockIdx.z;

    const int rb = __builtin_amdgcn_readfirstlane(c0 + 8 * wave);
    const float* __restrict__ Wr = W + (size_t)rb * CC;

    float inv_c[8], add_c[8];
#pragma unroll
    for (int i = 0; i < 8; ++i) {
        int c = rb + i;
        float g = bn_g[3 * CC + c];
        float bt = bn_b[3 * CC + c];
        float m = bn_m[3 * CC + c];
        float v = bn_v[3 * CC + c];
        float inv = g / sqrtf(v + EPS);
        inv_c[i] = inv;
        add_c[i] = bt - m * inv;
    }

    const int skk[4] = {tid >> 6, (tid + 256) >> 6, (tid + 512) >> 6, (tid + 768) >> 6};
    const int scf = tid & 63;
    const int shft = 4 * (scf & 7);

    auto ldw = [&](int k0, int s) -> uint32_t {
        return s3p[(size_t)(b * CC + k0 + skk[s]) * NW + (n0 >> 5) + (scf >> 3)];
    };
    auto expand = [&](uint32_t word) -> float4 {
        float4 xv;
        xv.x = (float)((word >> (shft + 0)) & 1u);
        xv.y = (float)((word >> (shft + 1)) & 1u);
        xv.z = (float)((word >> (shft + 2)) & 1u);
        xv.w = (float)((word >> (shft + 3)) & 1u);
        return xv;
    };

    float acc[8][4];
#pragma unroll
    for (int i = 0; i < 8; ++i)
#pragma unroll
        for (int j = 0; j < 4; ++j) acc[i][j] = 0.0f;

    uint32_t pw[4];
#pragma unroll
    for (int s = 0; s < 4; ++s) pw[s] = ldw(0, s);
#pragma unroll
    for (int s = 0; s < 4; ++s)
        *(float4*)&Xs[skk[s]][4 * scf] = expand(pw[s]);
    __syncthreads();

    for (int k0 = 0; k0 < CC; k0 += 16) {
        const bool hasNext = (k0 + 16 < CC);
        if (hasNext) {
#pragma unroll
            for (int s = 0; s < 4; ++s) pw[s] = ldw(k0 + 16, s);
        }
#pragma unroll 1
        for (int h = 0; h < 2; ++h) {
            float4 xf[8];
#pragma unroll
            for (int u = 0; u < 8; ++u)
                xf[u] = *(float4*)&Xs[8 * h + u][4 * lane];
#pragma unroll
            for (int r = 0; r < 8; ++r) {
#pragma unroll
                for (int u = 0; u < 8; ++u) {
                    float a = Wr[(size_t)r * CC + k0 + 8 * h + u];  // s_load
                    acc[r][0] += a * xf[u].x;
                    acc[r][1] += a * xf[u].y;
                    acc[r][2] += a * xf[u].z;
                    acc[r][3] += a * xf[u].w;
                }
            }
        }
        if (hasNext) {
            __syncthreads();
#pragma unroll
            for (int s = 0; s < 4; ++s)
                *(float4*)&Xs[skk[s]][4 * scf] = expand(pw[s]);
            __syncthreads();
        }
    }

    float* ob = out + (size_t)b * CC * NN;
#pragma unroll
    for (int r = 0; r < 8; ++r) {
        float4 o;
        o.x = acc[r][0] * inv_c[r] + add_c[r];
        o.y = acc[r][1] * inv_c[r] + add_c[r];
        o.z = acc[r][2] * inv_c[r] + add_c[r];
        o.w = acc[r][3] * inv_c[r] + add_c[r];
        *(float4*)&ob[(size_t)(rb + r) * NN + n0 + 4 * lane] = o;
    }
}

// ---------------------------------------------------------------------------
extern "C" void kernel_launch(void* const* d_in, const int* in_sizes, int n_in,
                              void* d_out, int out_size, void* d_ws, size_t ws_size,
                              hipStream_t stream) {
    const float* x     = (const float*)d_in[0];
    const float* wq    = (const float*)d_in[1];
    const float* wk    = (const float*)d_in[2];
    const float* wv    = (const float*)d_in[3];
    const float* wproj = (const float*)d_in[4];
    const float* bng   = (const float*)d_in[5];
    const float* bnb   = (const float*)d_in[6];
    const float* bnm   = (const float*)d_in[7];
    const float* bnv   = (const float*)d_in[8];

    const size_t PK = (size_t)BB * CC * NW;            // 2 MiB each
    uint32_t* qp  = (uint32_t*)d_ws;
    uint32_t* kp  = qp + PK;
    uint32_t* vp  = kp + PK;
    uint32_t* s3p = vp + PK;                           // total 8 MiB

    dim3 gconv(NN / 256, CC / 32, 3 * BE);             // z = w*16 + be
    conv_bn_lif_kernel<<<gconv, 256, 0, stream>>>(x, wq, wk, wv, bng, bnb, bnm, bnv,
                                                  qp, kp, vp);

    dim3 gattn(4, NH, BE);
    attn_lif_kernel<<<gattn, 256, 0, stream>>>(qp, kp, vp, s3p);

    dim3 gproj(NN / 256, CC / 32, BB);
    proj_kernel<<<gproj, 256, 0, stream>>>(s3p, wproj, bng, bnb, bnm, bnv, (float*)d_out);
}